// Round 3
// baseline (202.022 us; speedup 1.0000x reference)
//
#include <hip/hip_runtime.h>

#define EPS 1e-5f

typedef float vf4 __attribute__((ext_vector_type(4)));  // clang vector: builtin-friendly

__device__ __forceinline__ int f2i(float x) { return __builtin_bit_cast(int, x); }
__device__ __forceinline__ float i2f(int x) { return __builtin_bit_cast(float, x); }

// DPP quad_perm move: returns partner lane's value (pattern CTRL), VALU pipe.
template <int CTRL>
__device__ __forceinline__ float dpp_move(float x) {
    return i2f(__builtin_amdgcn_update_dpp(0, f2i(x), CTRL, 0xF, 0xF, true));
}

// ds_swizzle xor-exchange (BitMode), DS pipe.
template <int IMM>
__device__ __forceinline__ float swz(float x) {
    return i2f(__builtin_amdgcn_ds_swizzle(f2i(x), IMM));
}

// permlane16_swap pair butterfly over lane-bit 4 (VALU pipe, no DS):
// swap(p,q) gathers {lo16-halves} into one reg and {hi16-halves} into the
// other; S=A+B, D=A-B; swapping back scatters sum into the lo half and diff
// into the hi half of both p and q — exactly the lane-bit-4 butterfly.
__device__ __forceinline__ void pl16_bfly(float& p, float& q) {
    auto r1 = __builtin_amdgcn_permlane16_swap(f2i(p), f2i(q), false, false);
    const float A = i2f(r1[0]), B = i2f(r1[1]);
    const float S = A + B, D = A - B;
    auto r2 = __builtin_amdgcn_permlane16_swap(f2i(S), f2i(D), false, false);
    p = i2f(r2[0]);
    q = i2f(r2[1]);
}

// permlane32_swap pair butterfly over lane-bit 5 (VALU pipe, no DS).
__device__ __forceinline__ void pl32_bfly(float& p, float& q) {
    auto r1 = __builtin_amdgcn_permlane32_swap(f2i(p), f2i(q), false, false);
    const float A = i2f(r1[0]), B = i2f(r1[1]);
    const float S = A + B, D = A - B;
    auto r2 = __builtin_amdgcn_permlane32_swap(f2i(S), f2i(D), false, false);
    p = i2f(r2[0]);
    q = i2f(r2[1]);
}

// ---------------- Pass 1: sum of squares of raw input (Parseval shortcut) ----
// HtH = 1024*I and golay^2 = 1, so mean(x_trans^2) = 1024*mean(x^2): the
// reduction needs only the raw input. 2048 blocks x 256 thr x 16 float4.
__global__ __launch_bounds__(256) void sumsq_kernel(const float4* __restrict__ x4,
                                                    float* __restrict__ partial) {
    __shared__ float sbuf[4];
    const int t = threadIdx.x;
    const size_t base = (size_t)blockIdx.x * 4096 + t;
    float s = 0.f;
#pragma unroll
    for (int k = 0; k < 16; ++k) {
        float4 v = x4[base + (size_t)k * 256];
        s += v.x * v.x + v.y * v.y + v.z * v.z + v.w * v.w;
    }
#pragma unroll
    for (int off = 32; off >= 1; off >>= 1) s += __shfl_down(s, off, 64);
    if ((t & 63) == 0) sbuf[t >> 6] = s;
    __syncthreads();
    if (t == 0) partial[blockIdx.x] = sbuf[0] + sbuf[1] + sbuf[2] + sbuf[3];
}

// ---------------- Pass 2: reduce partials -> scale ---------------------------
__global__ __launch_bounds__(256) void finalize_kernel(const float* __restrict__ partial,
                                                       float* __restrict__ scale) {
    __shared__ float sbuf[4];
    const int t = threadIdx.x;
    float s = 0.f;
#pragma unroll
    for (int k = 0; k < 8; ++k) s += partial[t + k * 256];
#pragma unroll
    for (int off = 32; off >= 1; off >>= 1) s += __shfl_down(s, off, 64);
    if ((t & 63) == 0) sbuf[t >> 6] = s;
    __syncthreads();
    if (t == 0) {
        const float total = sbuf[0] + sbuf[1] + sbuf[2] + sbuf[3];
        const float mean_trans = total * (1.0f / 32768.0f);  // 1024*total/33554432
        const float alpha = sqrtf(mean_trans + EPS);
        scale[0] = 1.0f / (alpha + EPS);
    }
}

// ---------------- Pass 3: golay-modulate + FWHT-1024 + scale -----------------
// One wave per row, 4 rows/block. Lane l owns elements [l*16, l*16+16).
// Element bits 0-3: in-register. Lane bits 0-1: DPP quad_perm. Lane bits 2-3:
// ds_swizzle. Lane bits 4-5: permlane{16,32}_swap pair butterflies.
// All butterfly stages commute, so any order is valid.
__global__ __launch_bounds__(256) void fwht_kernel(const float4* __restrict__ x4,
                                                   const float4* __restrict__ g4,
                                                   const float* __restrict__ scale,
                                                   vf4* __restrict__ out4) {
    const int lane = threadIdx.x & 63;
    const int wid = threadIdx.x >> 6;
    const size_t row = (size_t)blockIdx.x * 4 + wid;
    const float4* xr = x4 + row * 256;
    vf4* orow = out4 + row * 256;

    float e[16];
#pragma unroll
    for (int q = 0; q < 4; ++q) {
        float4 v = xr[lane * 4 + q];
        float4 g = g4[lane * 4 + q];
        e[q * 4 + 0] = v.x * g.x;
        e[q * 4 + 1] = v.y * g.y;
        e[q * 4 + 2] = v.z * g.z;
        e[q * 4 + 3] = v.w * g.w;
    }

    // In-register FWHT over element bits 0-3.
#pragma unroll
    for (int h = 1; h < 16; h <<= 1) {
#pragma unroll
        for (int i = 0; i < 16; ++i) {
            if (!(i & h)) {
                const float a = e[i], b = e[i | h];
                e[i] = a + b;
                e[i | h] = a - b;
            }
        }
    }

    // Lane-bit 0: quad_perm [1,0,3,2] = 0xB1.  out = partner + (up ? -e : e)
    {
        const bool up = (lane & 1) != 0;
#pragma unroll
        for (int i = 0; i < 16; ++i) {
            const float se = up ? -e[i] : e[i];
            e[i] = dpp_move<0xB1>(e[i]) + se;
        }
    }
    // Lane-bit 1: quad_perm [2,3,0,1] = 0x4E.
    {
        const bool up = (lane & 2) != 0;
#pragma unroll
        for (int i = 0; i < 16; ++i) {
            const float se = up ? -e[i] : e[i];
            e[i] = dpp_move<0x4E>(e[i]) + se;
        }
    }
    // Lane-bit 2: ds_swizzle xor 4 (0x101F).
    {
        const bool up = (lane & 4) != 0;
#pragma unroll
        for (int i = 0; i < 16; ++i) {
            const float se = up ? -e[i] : e[i];
            e[i] = swz<0x101F>(e[i]) + se;
        }
    }
    // Lane-bit 3: ds_swizzle xor 8 (0x201F).
    {
        const bool up = (lane & 8) != 0;
#pragma unroll
        for (int i = 0; i < 16; ++i) {
            const float se = up ? -e[i] : e[i];
            e[i] = swz<0x201F>(e[i]) + se;
        }
    }
    // Lane-bit 4: permlane16_swap pair butterflies.
#pragma unroll
    for (int i = 0; i < 16; i += 2) pl16_bfly(e[i], e[i + 1]);
    // Lane-bit 5: permlane32_swap pair butterflies.
#pragma unroll
    for (int i = 0; i < 16; i += 2) pl32_bfly(e[i], e[i + 1]);

    const float s = scale[0];
#pragma unroll
    for (int q = 0; q < 4; ++q) {
        vf4 v;
        v.x = e[q * 4 + 0] * s;
        v.y = e[q * 4 + 1] * s;
        v.z = e[q * 4 + 2] * s;
        v.w = e[q * 4 + 3] * s;
        __builtin_nontemporal_store(v, &orow[lane * 4 + q]);
    }
}

extern "C" void kernel_launch(void* const* d_in, const int* in_sizes, int n_in,
                              void* d_out, int out_size, void* d_ws, size_t ws_size,
                              hipStream_t stream) {
    const float* x = (const float*)d_in[0];
    const float* golay = (const float*)d_in[1];
    float* out = (float*)d_out;
    float* ws = (float*)d_ws;
    float* partial = ws;       // 2048 floats
    float* scale = ws + 2048;  // 1 float

    sumsq_kernel<<<2048, 256, 0, stream>>>((const float4*)x, partial);
    finalize_kernel<<<1, 256, 0, stream>>>(partial, scale);
    fwht_kernel<<<8192, 256, 0, stream>>>((const float4*)x, (const float4*)golay,
                                          scale, (vf4*)out);
}

// Round 4
// 66.229 us; speedup vs baseline: 3.0504x; 3.0504x over previous
//
#include <hip/hip_runtime.h>

#define EPS 1e-5f

__device__ __forceinline__ int f2i(float x) { return __builtin_bit_cast(int, x); }
__device__ __forceinline__ float i2f(int x) { return __builtin_bit_cast(float, x); }

// DPP quad_perm move: returns partner lane's value (pattern CTRL), VALU pipe.
template <int CTRL>
__device__ __forceinline__ float dpp_move(float x) {
    return i2f(__builtin_amdgcn_update_dpp(0, f2i(x), CTRL, 0xF, 0xF, true));
}

// ds_swizzle xor-exchange (BitMode), DS pipe.
template <int IMM>
__device__ __forceinline__ float swz(float x) {
    return i2f(__builtin_amdgcn_ds_swizzle(f2i(x), IMM));
}

// permlane16_swap pair butterfly over lane-bit 4 (VALU pipe, no DS).
// Verified exact in R3 (absmax 0.0).
__device__ __forceinline__ void pl16_bfly(float& p, float& q) {
    auto r1 = __builtin_amdgcn_permlane16_swap(f2i(p), f2i(q), false, false);
    const float A = i2f(r1[0]), B = i2f(r1[1]);
    const float S = A + B, D = A - B;
    auto r2 = __builtin_amdgcn_permlane16_swap(f2i(S), f2i(D), false, false);
    p = i2f(r2[0]);
    q = i2f(r2[1]);
}

// permlane32_swap pair butterfly over lane-bit 5 (VALU pipe, no DS).
__device__ __forceinline__ void pl32_bfly(float& p, float& q) {
    auto r1 = __builtin_amdgcn_permlane32_swap(f2i(p), f2i(q), false, false);
    const float A = i2f(r1[0]), B = i2f(r1[1]);
    const float S = A + B, D = A - B;
    auto r2 = __builtin_amdgcn_permlane32_swap(f2i(S), f2i(D), false, false);
    p = i2f(r2[0]);
    q = i2f(r2[1]);
}

// ---------------- Pass 1: sum of squares of raw input (Parseval shortcut) ----
// HtH = 1024*I and golay^2 = 1, so mean(x_trans^2) = 1024*mean(x^2): the
// reduction needs only the raw input. 2048 blocks x 256 thr x 16 float4.
__global__ __launch_bounds__(256) void sumsq_kernel(const float4* __restrict__ x4,
                                                    float* __restrict__ partial) {
    __shared__ float sbuf[4];
    const int t = threadIdx.x;
    const size_t base = (size_t)blockIdx.x * 4096 + t;
    float s = 0.f;
#pragma unroll
    for (int k = 0; k < 16; ++k) {
        float4 v = x4[base + (size_t)k * 256];
        s += v.x * v.x + v.y * v.y + v.z * v.z + v.w * v.w;
    }
#pragma unroll
    for (int off = 32; off >= 1; off >>= 1) s += __shfl_down(s, off, 64);
    if ((t & 63) == 0) sbuf[t >> 6] = s;
    __syncthreads();
    if (t == 0) partial[blockIdx.x] = sbuf[0] + sbuf[1] + sbuf[2] + sbuf[3];
}

// ---------------- Pass 2: reduce partials -> scale ---------------------------
__global__ __launch_bounds__(256) void finalize_kernel(const float* __restrict__ partial,
                                                       float* __restrict__ scale) {
    __shared__ float sbuf[4];
    const int t = threadIdx.x;
    float s = 0.f;
#pragma unroll
    for (int k = 0; k < 8; ++k) s += partial[t + k * 256];
#pragma unroll
    for (int off = 32; off >= 1; off >>= 1) s += __shfl_down(s, off, 64);
    if ((t & 63) == 0) sbuf[t >> 6] = s;
    __syncthreads();
    if (t == 0) {
        const float total = sbuf[0] + sbuf[1] + sbuf[2] + sbuf[3];
        const float mean_trans = total * (1.0f / 32768.0f);  // 1024*total/33554432
        const float alpha = sqrtf(mean_trans + EPS);
        scale[0] = 1.0f / (alpha + EPS);
    }
}

// ---------------- Pass 3: golay-modulate + FWHT-1024 + scale -----------------
// One wave per row, 4 rows/block. INTERLEAVED ownership: lane l holds float4
// chunks at float4-index {l + 64k, k=0..3}, i.e. element n = 256k + 4l + j.
// => every load/store instruction is 64 consecutive float4s = 1 KB coalesced.
// Element bits: 0-1 = j (in-reg), 2-7 = lane bits (cross-lane), 8-9 = k (in-reg).
// Stages commute, so order is free.
__global__ __launch_bounds__(256) void fwht_kernel(const float4* __restrict__ x4,
                                                   const float4* __restrict__ g4,
                                                   const float* __restrict__ scale,
                                                   float4* __restrict__ out4) {
    const int lane = threadIdx.x & 63;
    const int wid = threadIdx.x >> 6;
    const size_t row = (size_t)blockIdx.x * 4 + wid;
    const float4* xr = x4 + row * 256;
    float4* orow = out4 + row * 256;

    float e[16];
#pragma unroll
    for (int k = 0; k < 4; ++k) {
        float4 v = xr[lane + 64 * k];
        float4 g = g4[lane + 64 * k];
        e[k * 4 + 0] = v.x * g.x;
        e[k * 4 + 1] = v.y * g.y;
        e[k * 4 + 2] = v.z * g.z;
        e[k * 4 + 3] = v.w * g.w;
    }

    // In-register FWHT over reg-index bits: bits 0-1 of i = element bits 0-1,
    // bits 2-3 of i = element bits 8-9. (i = k*4 + j)
#pragma unroll
    for (int h = 1; h < 16; h <<= 1) {
#pragma unroll
        for (int i = 0; i < 16; ++i) {
            if (!(i & h)) {
                const float a = e[i], b = e[i | h];
                e[i] = a + b;
                e[i | h] = a - b;
            }
        }
    }

    // Lane-bit 0 (element bit 2): quad_perm [1,0,3,2] = 0xB1.
    {
        const bool up = (lane & 1) != 0;
#pragma unroll
        for (int i = 0; i < 16; ++i) {
            const float se = up ? -e[i] : e[i];
            e[i] = dpp_move<0xB1>(e[i]) + se;
        }
    }
    // Lane-bit 1 (element bit 3): quad_perm [2,3,0,1] = 0x4E.
    {
        const bool up = (lane & 2) != 0;
#pragma unroll
        for (int i = 0; i < 16; ++i) {
            const float se = up ? -e[i] : e[i];
            e[i] = dpp_move<0x4E>(e[i]) + se;
        }
    }
    // Lane-bit 2 (element bit 4): ds_swizzle xor 4.
    {
        const bool up = (lane & 4) != 0;
#pragma unroll
        for (int i = 0; i < 16; ++i) {
            const float se = up ? -e[i] : e[i];
            e[i] = swz<0x101F>(e[i]) + se;
        }
    }
    // Lane-bit 3 (element bit 5): ds_swizzle xor 8.
    {
        const bool up = (lane & 8) != 0;
#pragma unroll
        for (int i = 0; i < 16; ++i) {
            const float se = up ? -e[i] : e[i];
            e[i] = swz<0x201F>(e[i]) + se;
        }
    }
    // Lane-bit 4 (element bit 6): permlane16_swap pair butterflies.
#pragma unroll
    for (int i = 0; i < 16; i += 2) pl16_bfly(e[i], e[i + 1]);
    // Lane-bit 5 (element bit 7): permlane32_swap pair butterflies.
#pragma unroll
    for (int i = 0; i < 16; i += 2) pl32_bfly(e[i], e[i + 1]);

    const float s = scale[0];
#pragma unroll
    for (int k = 0; k < 4; ++k) {
        float4 v;
        v.x = e[k * 4 + 0] * s;
        v.y = e[k * 4 + 1] * s;
        v.z = e[k * 4 + 2] * s;
        v.w = e[k * 4 + 3] * s;
        orow[lane + 64 * k] = v;
    }
}

extern "C" void kernel_launch(void* const* d_in, const int* in_sizes, int n_in,
                              void* d_out, int out_size, void* d_ws, size_t ws_size,
                              hipStream_t stream) {
    const float* x = (const float*)d_in[0];
    const float* golay = (const float*)d_in[1];
    float* out = (float*)d_out;
    float* ws = (float*)d_ws;
    float* partial = ws;       // 2048 floats
    float* scale = ws + 2048;  // 1 float

    sumsq_kernel<<<2048, 256, 0, stream>>>((const float4*)x, partial);
    finalize_kernel<<<1, 256, 0, stream>>>(partial, scale);
    fwht_kernel<<<8192, 256, 0, stream>>>((const float4*)x, (const float4*)golay,
                                          scale, (float4*)out);
}

// Round 5
// 63.745 us; speedup vs baseline: 3.1692x; 1.0390x over previous
//
#include <hip/hip_runtime.h>

#define EPS 1e-5f

typedef float vf4 __attribute__((ext_vector_type(4)));  // clang vector: NT-builtin-friendly

__device__ __forceinline__ int f2i(float x) { return __builtin_bit_cast(int, x); }
__device__ __forceinline__ float i2f(int x) { return __builtin_bit_cast(float, x); }

// DPP quad_perm move: returns partner lane's value (pattern CTRL), VALU pipe.
template <int CTRL>
__device__ __forceinline__ float dpp_move(float x) {
    return i2f(__builtin_amdgcn_update_dpp(0, f2i(x), CTRL, 0xF, 0xF, true));
}

// ds_swizzle xor-exchange (BitMode), DS pipe.
template <int IMM>
__device__ __forceinline__ float swz(float x) {
    return i2f(__builtin_amdgcn_ds_swizzle(f2i(x), IMM));
}

// permlane16_swap pair butterfly over lane-bit 4 (VALU pipe, no DS).
// Verified exact in R3/R4 (absmax 0.0 / 0.0156).
__device__ __forceinline__ void pl16_bfly(float& p, float& q) {
    auto r1 = __builtin_amdgcn_permlane16_swap(f2i(p), f2i(q), false, false);
    const float A = i2f(r1[0]), B = i2f(r1[1]);
    const float S = A + B, D = A - B;
    auto r2 = __builtin_amdgcn_permlane16_swap(f2i(S), f2i(D), false, false);
    p = i2f(r2[0]);
    q = i2f(r2[1]);
}

// permlane32_swap pair butterfly over lane-bit 5 (VALU pipe, no DS).
__device__ __forceinline__ void pl32_bfly(float& p, float& q) {
    auto r1 = __builtin_amdgcn_permlane32_swap(f2i(p), f2i(q), false, false);
    const float A = i2f(r1[0]), B = i2f(r1[1]);
    const float S = A + B, D = A - B;
    auto r2 = __builtin_amdgcn_permlane32_swap(f2i(S), f2i(D), false, false);
    p = i2f(r2[0]);
    q = i2f(r2[1]);
}

// ---------------- Pass 1: sum of squares of raw input (Parseval shortcut) ----
// HtH = 1024*I and golay^2 = 1, so mean(x_trans^2) = 1024*mean(x^2): the
// reduction needs only the raw input. 2048 blocks x 256 thr x 16 float4.
// Plain (caching) loads on purpose: warms L3 with x for the fwht pass.
__global__ __launch_bounds__(256) void sumsq_kernel(const float4* __restrict__ x4,
                                                    float* __restrict__ partial) {
    __shared__ float sbuf[4];
    const int t = threadIdx.x;
    const size_t base = (size_t)blockIdx.x * 4096 + t;
    float s = 0.f;
#pragma unroll
    for (int k = 0; k < 16; ++k) {
        float4 v = x4[base + (size_t)k * 256];
        s += v.x * v.x + v.y * v.y + v.z * v.z + v.w * v.w;
    }
#pragma unroll
    for (int off = 32; off >= 1; off >>= 1) s += __shfl_down(s, off, 64);
    if ((t & 63) == 0) sbuf[t >> 6] = s;
    __syncthreads();
    if (t == 0) partial[blockIdx.x] = sbuf[0] + sbuf[1] + sbuf[2] + sbuf[3];
}

// ---------------- Pass 2: golay-modulate + FWHT-1024 + inline-finalize -------
// One wave per row, 4 rows/block. INTERLEAVED ownership: lane l holds float4
// chunks at float4-index {l + 64k, k=0..3}, i.e. element n = 256k + 4l + j.
// => every load/store instruction is 64 consecutive float4s = 1 KB coalesced.
// Element bits: 0-1 = j (in-reg), 2-7 = lane bits (cross-lane), 8-9 = k (in-reg).
// Each block redundantly reduces the 2048 sumsq partials (8 KB, L2-hot) ->
// identical deterministic scale in every block; kills the finalize dispatch.
// Output uses nontemporal stores so the 134 MB stream doesn't evict x from L3.
__global__ __launch_bounds__(256) void fwht_kernel(const float4* __restrict__ x4,
                                                   const float4* __restrict__ g4,
                                                   const float* __restrict__ partial,
                                                   vf4* __restrict__ out4) {
    __shared__ float sbuf[4];
    const int t = threadIdx.x;
    const int lane = t & 63;
    const int wid = t >> 6;
    const size_t row = (size_t)blockIdx.x * 4 + wid;
    const float4* xr = x4 + row * 256;
    vf4* orow = out4 + row * 256;

    float e[16];
#pragma unroll
    for (int k = 0; k < 4; ++k) {
        float4 v = xr[lane + 64 * k];
        float4 g = g4[lane + 64 * k];
        e[k * 4 + 0] = v.x * g.x;
        e[k * 4 + 1] = v.y * g.y;
        e[k * 4 + 2] = v.z * g.z;
        e[k * 4 + 3] = v.w * g.w;
    }

    // Inline finalize: block-redundant reduce of the 2048 partials.
    float ps = 0.f;
#pragma unroll
    for (int k = 0; k < 8; ++k) ps += partial[t + k * 256];
#pragma unroll
    for (int off = 32; off >= 1; off >>= 1) ps += __shfl_down(ps, off, 64);
    if (lane == 0) sbuf[wid] = ps;
    __syncthreads();

    // In-register FWHT over reg-index bits: bits 0-1 of i = element bits 0-1,
    // bits 2-3 of i = element bits 8-9. (i = k*4 + j)
#pragma unroll
    for (int h = 1; h < 16; h <<= 1) {
#pragma unroll
        for (int i = 0; i < 16; ++i) {
            if (!(i & h)) {
                const float a = e[i], b = e[i | h];
                e[i] = a + b;
                e[i | h] = a - b;
            }
        }
    }

    // Lane-bit 0 (element bit 2): quad_perm [1,0,3,2] = 0xB1.
    {
        const bool up = (lane & 1) != 0;
#pragma unroll
        for (int i = 0; i < 16; ++i) {
            const float se = up ? -e[i] : e[i];
            e[i] = dpp_move<0xB1>(e[i]) + se;
        }
    }
    // Lane-bit 1 (element bit 3): quad_perm [2,3,0,1] = 0x4E.
    {
        const bool up = (lane & 2) != 0;
#pragma unroll
        for (int i = 0; i < 16; ++i) {
            const float se = up ? -e[i] : e[i];
            e[i] = dpp_move<0x4E>(e[i]) + se;
        }
    }
    // Lane-bit 2 (element bit 4): ds_swizzle xor 4.
    {
        const bool up = (lane & 4) != 0;
#pragma unroll
        for (int i = 0; i < 16; ++i) {
            const float se = up ? -e[i] : e[i];
            e[i] = swz<0x101F>(e[i]) + se;
        }
    }
    // Lane-bit 3 (element bit 5): ds_swizzle xor 8.
    {
        const bool up = (lane & 8) != 0;
#pragma unroll
        for (int i = 0; i < 16; ++i) {
            const float se = up ? -e[i] : e[i];
            e[i] = swz<0x201F>(e[i]) + se;
        }
    }
    // Lane-bit 4 (element bit 6): permlane16_swap pair butterflies.
#pragma unroll
    for (int i = 0; i < 16; i += 2) pl16_bfly(e[i], e[i + 1]);
    // Lane-bit 5 (element bit 7): permlane32_swap pair butterflies.
#pragma unroll
    for (int i = 0; i < 16; i += 2) pl32_bfly(e[i], e[i + 1]);

    // Scale from the redundant reduce (identical in every block).
    const float total = sbuf[0] + sbuf[1] + sbuf[2] + sbuf[3];
    const float mean_trans = total * (1.0f / 32768.0f);  // 1024*total/33554432
    const float s = 1.0f / (sqrtf(mean_trans + EPS) + EPS);

#pragma unroll
    for (int k = 0; k < 4; ++k) {
        vf4 v;
        v.x = e[k * 4 + 0] * s;
        v.y = e[k * 4 + 1] * s;
        v.z = e[k * 4 + 2] * s;
        v.w = e[k * 4 + 3] * s;
        __builtin_nontemporal_store(v, &orow[lane + 64 * k]);
    }
}

extern "C" void kernel_launch(void* const* d_in, const int* in_sizes, int n_in,
                              void* d_out, int out_size, void* d_ws, size_t ws_size,
                              hipStream_t stream) {
    const float* x = (const float*)d_in[0];
    const float* golay = (const float*)d_in[1];
    float* out = (float*)d_out;
    float* ws = (float*)d_ws;
    float* partial = ws;  // 2048 floats

    sumsq_kernel<<<2048, 256, 0, stream>>>((const float4*)x, partial);
    fwht_kernel<<<8192, 256, 0, stream>>>((const float4*)x, (const float4*)golay,
                                          partial, (vf4*)out);
}